// Round 10
// baseline (73.591 us; speedup 1.0000x reference)
//
#include <hip/hip_runtime.h>
#include <hip/hip_bf16.h>
#include <math.h>

#define SEQ   2048
#define H     1024
#define VOCAB 32000
#define GRID2 2048
#define NTHR  256

__device__ inline float4 ld4(const float* p) { return *reinterpret_cast<const float4*>(p); }
__device__ inline float dot4(float4 a, float4 b) { return a.x*b.x + a.y*b.y + a.z*b.z + a.w*b.w; }
__device__ inline float sigmoidf(float x) { return 1.f / (1.f + expf(-x)); }

__device__ inline void omerge(float& m, float& s, float m2, float s2) {
    if (m2 > m) { s = s * __expf(m - m2) + s2; m = m2; }
    else if (s2 != 0.f) { s += s2 * __expf(m2 - m); }
}
__device__ inline float waveSum(float v) {
#pragma unroll
    for (int off = 32; off > 0; off >>= 1) v += __shfl_down(v, off, 64);
    return v;
}
__device__ inline void waveOmerge(float& m, float& s) {
#pragma unroll
    for (int off = 32; off > 0; off >>= 1) {
        float m2 = __shfl_down(m, off, 64), ss = __shfl_down(s, off, 64);
        omerge(m, s, m2, ss);
    }
}

// ---- sharded device-scope signal/wait (16 shards x 128 B apart) -----------
#define SHARDS 16
#define SHSTRIDE 32

__device__ inline void blockSignalSh(unsigned* f) {
    __syncthreads();
    if (threadIdx.x == 0) {
        __threadfence();
        __hip_atomic_fetch_add(&f[(blockIdx.x & (SHARDS - 1)) * SHSTRIDE], 1u,
                               __ATOMIC_RELEASE, __HIP_MEMORY_SCOPE_AGENT);
    }
}
__device__ inline unsigned shSum(unsigned* f) {
    unsigned sum = 0;
#pragma unroll
    for (int q = 0; q < SHARDS; ++q)
        sum += __hip_atomic_load(&f[q * SHSTRIDE], __ATOMIC_RELAXED,
                                 __HIP_MEMORY_SCOPE_AGENT);
    return sum;
}
__device__ inline void blockWaitSlow(unsigned* f, unsigned target) {
    if (threadIdx.x == 0) {
        int it = 0;
        while (shSum(f) < target) {
            if (it < 2)       __builtin_amdgcn_s_sleep(1);
            else if (it < 4)  __builtin_amdgcn_s_sleep(2);
            else if (it < 6)  __builtin_amdgcn_s_sleep(4);
            else if (it < 8)  __builtin_amdgcn_s_sleep(8);
            else if (it < 10) __builtin_amdgcn_s_sleep(16);
            else if (it < 12) __builtin_amdgcn_s_sleep(32);
            else              __builtin_amdgcn_s_sleep(64);
            ++it;
        }
        __threadfence();
    }
    __syncthreads();
}
__device__ inline void blockWaitFast(unsigned* f, unsigned target) {
    if (threadIdx.x == 0) {
        int it = 0;
        while (shSum(f) < target) {
            if (it < 2)      __builtin_amdgcn_s_sleep(1);
            else if (it < 4) __builtin_amdgcn_s_sleep(2);
            else if (it < 6) __builtin_amdgcn_s_sleep(4);
            else             __builtin_amdgcn_s_sleep(8);
            ++it;
        }
        __threadfence();
    }
    __syncthreads();
}

// ws layout:
//  uints [0..2816): f_h @0, f_u @512, f_e @1024, f_ctx @1536, f_l @2048
//  floats: h @2816 [1024] } vcat contiguous [2048]
//          ctx @3840 [1024] }
//          u @4864 [1024]
//          part_e = (float2*)(ws+5888)  [512]   (1024 floats)
//          part_l = (float2*)(ws+6912)  [2048]  (4096 floats)
//          ctxp @11008 [512*1024]               (2 MB)
#define WS_NEED_FLOATS (11008 + 512 * 1024)

__global__ __launch_bounds__(NTHR) void k_init(float* __restrict__ ws) {
    const int t = threadIdx.x;
    unsigned* fl = (unsigned*)ws;
    for (int k = t; k < 2816; k += NTHR) fl[k] = 0u;
    float* ctx = ws + 3840;
    float* u   = ws + 4864;
    for (int k = t; k < H; k += NTHR) { u[k] = 0.f; ctx[k] = 0.f; }
}

__global__ __launch_bounds__(NTHR, 8) void k_main(
        const float* __restrict__ emb,  const float* __restrict__ lctx,
        const float* __restrict__ h0,   const float* __restrict__ W_ih,
        const float* __restrict__ W_hh, const float* __restrict__ b_ih,
        const float* __restrict__ b_hh, const int* __restrict__ widx,
        const float* __restrict__ enc,  const float* __restrict__ Wa,
        const float* __restrict__ Wl,   const float* __restrict__ bl,
        float* __restrict__ ws, float* __restrict__ out) {
    const int bid = blockIdx.x, t = threadIdx.x;
    const int wid = t >> 6, lane = t & 63;

    unsigned* f_h   = (unsigned*)ws + 0;
    unsigned* f_u   = (unsigned*)ws + 512;
    unsigned* f_e   = (unsigned*)ws + 1024;
    unsigned* f_ctx = (unsigned*)ws + 1536;
    unsigned* f_l   = (unsigned*)ws + 2048;
    float*  vcat   = ws + 2816;                 // [2048] = h | ctx
    float*  h      = vcat;
    float*  ctx    = vcat + H;
    float*  u      = ws + 4864;
    float2* part_e = (float2*)(ws + 5888);      // [512]
    float2* part_l = (float2*)(ws + 6912);      // [2048]
    float*  ctxp   = ws + 11008;                // [512*1024]

    __shared__ __align__(16) float encS[4][1024];   // 16 KB enc staging
    __shared__ float  lg[12];
    __shared__ float  shh[16];
    __shared__ float  se[8];
    __shared__ float2 s2[4];

    // ======== P1: LSTM — blocks 0..1023, one block per output j ===========
    if (bid < 1024) {
        const int j = bid;
        const int w = widx[0];                  // int64 LE, value < 32000
        const float* xep = emb + (size_t)w * H;
        const float* wi = W_ih + (size_t)j * (2 * H);
        const float* wg = W_ih + (size_t)(j + 2 * H) * (2 * H);
        const float* wo = W_ih + (size_t)(j + 3 * H) * (2 * H);
        const float* vi = W_hh + (size_t)j * H;
        const float* vg = W_hh + (size_t)(j + 2 * H) * H;
        const float* vo = W_hh + (size_t)(j + 3 * H) * H;
        const int e = t * 4;
        float4 x0 = ld4(xep + e), x1 = ld4(lctx + e), x2 = ld4(h0 + e);
        float ai = dot4(ld4(wi + e), x0) + dot4(ld4(wi + H + e), x1) + dot4(ld4(vi + e), x2);
        float ag = dot4(ld4(wg + e), x0) + dot4(ld4(wg + H + e), x1) + dot4(ld4(vg + e), x2);
        float ao = dot4(ld4(wo + e), x0) + dot4(ld4(wo + H + e), x1) + dot4(ld4(vo + e), x2);
        ai = waveSum(ai); ag = waveSum(ag); ao = waveSum(ao);
        if (lane == 0) { lg[wid*3] = ai; lg[wid*3+1] = ag; lg[wid*3+2] = ao; }
        __syncthreads();
        if (t == 0) {
            float gi = 0.f, gg = 0.f, go = 0.f;
            for (int q = 0; q < 4; ++q) { gi += lg[q*3]; gg += lg[q*3+1]; go += lg[q*3+2]; }
            gi += b_ih[j] + b_hh[j];
            gg += b_ih[j + 2*H] + b_hh[j + 2*H];
            go += b_ih[j + 3*H] + b_hh[j + 3*H];
            float c = sigmoidf(gi) * tanhf(gg);  // c0 == 0 -> f-gate dead
            h[j] = sigmoidf(go) * tanhf(c);
        }
        blockSignalSh(f_h);
    }

    if (bid >= 1024 && bid < 1536) {
        // ============== attention chain (512 blocks, ab in [0,512)) =======
        const int ab = bid - 1024;
        // --- u = Wa^T h (first 256 blocks only; contention 64) ---
        if (ab < 256) {
            blockWaitFast(f_h, 1024);
            const int rg = ab >> 2, kb = ab & 3;
            if (t < 16) shh[t] = h[rg * 16 + t];
            __syncthreads();
            const int k = kb * 256 + t;
            float acc = 0.f;
#pragma unroll
            for (int jj = 0; jj < 16; ++jj)
                acc += Wa[(size_t)(rg * 16 + jj) * H + k] * shh[jj];
            atomicAdd(&u[k], acc);
            blockSignalSh(f_u);
        }
        blockWaitFast(f_u, 256);
        // --- energies (4 rows/block, enc staged in LDS) + ctxp partial ---
        {
            const int r = ab * 4 + wid;
            const float* er = enc + (size_t)r * H;
            float acc = 0.f;
#pragma unroll
            for (int q = 0; q < 4; ++q) {
                const int e = q * 256 + lane * 4;
                float4 ev = ld4(er + e);
                *(float4*)&encS[wid][e] = ev;
                acc += dot4(ev, ld4(u + e));
            }
            acc = waveSum(acc);
            if (lane == 0) se[wid] = acc;
            __syncthreads();
            const float m = fmaxf(fmaxf(se[0], se[1]), fmaxf(se[2], se[3]));
            if (t == 0) {
                float s = __expf(se[0]-m) + __expf(se[1]-m)
                        + __expf(se[2]-m) + __expf(se[3]-m);
                part_e[ab] = make_float2(m, s);
            }
            const float w0 = __expf(se[0]-m), w1 = __expf(se[1]-m);
            const float w2 = __expf(se[2]-m), w3 = __expf(se[3]-m);
#pragma unroll
            for (int c = 0; c < 4; ++c) {
                const int k = c * 256 + t;
                ctxp[(size_t)ab * 1024 + k] = w0*encS[0][k] + w1*encS[1][k]
                                            + w2*encS[2][k] + w3*encS[3][k];
            }
        }
        blockSignalSh(f_e);
        blockWaitFast(f_e, 512);
        // --- exact ctx reduce: this block owns cols 2ab, 2ab+1 ---
        {
            float2 pa = part_e[t], pb = part_e[t + 256];
            float M = pa.x, S = pa.y;
            omerge(M, S, pb.x, pb.y);
            waveOmerge(M, S);
            if (lane == 0) s2[wid] = make_float2(M, S);
            __syncthreads();
            float Mg = s2[0].x, Sg = s2[0].y;
#pragma unroll
            for (int q = 1; q < 4; ++q) omerge(Mg, Sg, s2[q].x, s2[q].y);
            const float invS = 1.f / Sg;
            const float wb0 = __expf(pa.x - Mg);
            const float wb1 = __expf(pb.x - Mg);
#pragma unroll
            for (int c = 0; c < 2; ++c) {
                const int k = ab * 2 + c;
                float p = ctxp[(size_t)t * 1024 + k] * wb0
                        + ctxp[(size_t)(t + 256) * 1024 + k] * wb1;
                p = waveSum(p);
                __syncthreads();
                if (lane == 0) se[wid] = p;
                __syncthreads();
                if (t == 0) ctx[k] = (se[0] + se[1] + se[2] + se[3]) * invS;
            }
        }
        blockSignalSh(f_ctx);
        blockWaitFast(f_ctx, 512);
        // --- tail rows 30720..31999 (one row per wave, 1280 rows) ---
        {
            const int aw = ab * 4 + wid;          // 0..2047
            float lm = -INFINITY, ls = 0.f;
            if (aw < 1280) {
                const int r = 30720 + aw;
                const float* wr = Wl + (size_t)r * (2 * H);
                float a = 0.f;
#pragma unroll
                for (int q = 0; q < 8; ++q)
                    a += dot4(ld4(wr + q * 256 + lane * 4),
                              ld4(vcat + q * 256 + lane * 4));
                a = waveSum(a);
                if (lane == 0) {
                    float v = a + bl[r];
                    out[r] = v;
                    omerge(lm, ls, v, 1.f);
                }
            }
            if (lane == 0) s2[wid] = make_float2(lm, ls);
            __syncthreads();
            if (t == 0) {
                float M = s2[0].x, S = s2[0].y;
#pragma unroll
                for (int q = 1; q < 4; ++q) omerge(M, S, s2[q].x, s2[q].y);
                part_l[bid] = make_float2(M, S);
            }
            blockSignalSh(f_l);
        }
    } else {
        // ===== streamers (1536 blocks): rows 0..30719, 5 rows/wave ========
        const int sw = (bid < 1024) ? bid : bid - 512;   // 0..1535
        const int gw = sw * 4 + wid;                     // 0..6143
        const int r0 = gw * 5;
        blockWaitFast(f_h, 1024);
        float4 xv[4];
#pragma unroll
        for (int q = 0; q < 4; ++q) xv[q] = ld4(h + q * 256 + lane * 4);
        float acc5[5];
#pragma unroll
        for (int rr = 0; rr < 5; ++rr) {
            const float* wr = Wl + (size_t)(r0 + rr) * (2 * H);
            float a = 0.f;
#pragma unroll
            for (int q = 0; q < 4; ++q)
                a += dot4(ld4(wr + q * 256 + lane * 4), xv[q]);
            acc5[rr] = a;
        }
        blockWaitFast(f_ctx, 512);   // ---- ctx ready ----
#pragma unroll
        for (int q = 0; q < 4; ++q) xv[q] = ld4(ctx + q * 256 + lane * 4);
        float lm = -INFINITY, ls = 0.f;
#pragma unroll
        for (int rr = 0; rr < 5; ++rr) {
            const int r = r0 + rr;
            const float* wr = Wl + (size_t)r * (2 * H) + H;
            float a = acc5[rr];
#pragma unroll
            for (int q = 0; q < 4; ++q)
                a += dot4(ld4(wr + q * 256 + lane * 4), xv[q]);
            a = waveSum(a);
            if (lane == 0) {
                float v = a + bl[r];
                out[r] = v;
                omerge(lm, ls, v, 1.f);
            }
        }
        if (lane == 0) s2[wid] = make_float2(lm, ls);
        __syncthreads();
        if (t == 0) {
            float M = s2[0].x, S = s2[0].y;
#pragma unroll
            for (int q = 1; q < 4; ++q) omerge(M, S, s2[q].x, s2[q].y);
            part_l[bid] = make_float2(M, S);
        }
        blockSignalSh(f_l);
    }

    // ============ final: out = logits - lse (blocks 0..124) ================
    if (bid < 125) {
        blockWaitSlow(f_l, 2048);
        float m = -INFINITY, s = 0.f;
#pragma unroll
        for (int q = 0; q < 8; ++q) {
            float2 p = part_l[t + q * 256];
            omerge(m, s, p.x, p.y);
        }
        waveOmerge(m, s);
        if (lane == 0) s2[wid] = make_float2(m, s);
        __syncthreads();
        float M = s2[0].x, S = s2[0].y;
#pragma unroll
        for (int q = 1; q < 4; ++q) omerge(M, S, s2[q].x, s2[q].y);
        const float lse = M + logf(S);
        const int i = bid * 256 + t;              // 125*256 == 32000
        out[i] = out[i] - lse;
    }
}

// ======================= fallback path (round-5, proven 74.8 µs) ===========

__global__ __launch_bounds__(256) void k_lstm(
        const float* __restrict__ emb, const float* __restrict__ lctx,
        const float* __restrict__ h0,  const float* __restrict__ W_ih,
        const float* __restrict__ W_hh, const float* __restrict__ b_ih,
        const float* __restrict__ b_hh, const int* __restrict__ widx,
        float* __restrict__ h_out, float* __restrict__ u_zero,
        float* __restrict__ ctx_zero) {
    const int j = blockIdx.x, t = threadIdx.x;
    const int wid = t >> 6, lane = t & 63;
    if (j == 0) for (int k = t; k < H; k += 256) u_zero[k] = 0.f;
    if (j == 1) for (int k = t; k < H; k += 256) ctx_zero[k] = 0.f;
    const int w = widx[0];
    const float* embrow = emb + (size_t)w * H;
    const int ri = j, rg = j + 2 * H, ro = j + 3 * H;
    const float* wi_i = W_ih + (size_t)ri * (2 * H);
    const float* wi_g = W_ih + (size_t)rg * (2 * H);
    const float* wi_o = W_ih + (size_t)ro * (2 * H);
    const float* wh_i = W_hh + (size_t)ri * H;
    const float* wh_g = W_hh + (size_t)rg * H;
    const float* wh_o = W_hh + (size_t)ro * H;
    float ai = 0.f, ag = 0.f, ao = 0.f;
    { int e = t*4; float4 x = ld4(embrow+e);
      ai += dot4(ld4(wi_i+e),x); ag += dot4(ld4(wi_g+e),x); ao += dot4(ld4(wi_o+e),x); }
    { int e = t*4; float4 x = ld4(lctx+e);
      ai += dot4(ld4(wi_i+H+e),x); ag += dot4(ld4(wi_g+H+e),x); ao += dot4(ld4(wi_o+H+e),x); }
    { int e = t*4; float4 x = ld4(h0+e);
      ai += dot4(ld4(wh_i+e),x); ag += dot4(ld4(wh_g+e),x); ao += dot4(ld4(wh_o+e),x); }
    ai = waveSum(ai); ag = waveSum(ag); ao = waveSum(ao);
    __shared__ float lds[12];
    if (lane == 0) { lds[wid*3] = ai; lds[wid*3+1] = ag; lds[wid*3+2] = ao; }
    __syncthreads();
    if (t == 0) {
        float gi = 0.f, gg = 0.f, go = 0.f;
        for (int q = 0; q < 4; ++q) { gi += lds[q*3]; gg += lds[q*3+1]; go += lds[q*3+2]; }
        gi += b_ih[ri] + b_hh[ri];
        gg += b_ih[rg] + b_hh[rg];
        go += b_ih[ro] + b_hh[ro];
        float c = sigmoidf(gi) * tanhf(gg);
        h_out[j] = sigmoidf(go) * tanhf(c);
    }
}

__global__ __launch_bounds__(256) void k_wa(
        const float* __restrict__ Wa, const float* __restrict__ h,
        float* __restrict__ u) {
    const int k = blockIdx.x * 256 + threadIdx.x;
    const int j0 = blockIdx.y * 32;
    float acc = 0.f;
#pragma unroll 8
    for (int j = j0; j < j0 + 32; ++j) acc += Wa[(size_t)j * H + k] * h[j];
    atomicAdd(&u[k], acc);
}

__global__ __launch_bounds__(256) void k_energy(
        const float* __restrict__ enc, const float* __restrict__ u,
        float* __restrict__ energ, float2* __restrict__ part_e) {
    const int t = threadIdx.x, wid = t >> 6, lane = t & 63;
    const int row = blockIdx.x * 4 + wid;
    const float* er = enc + (size_t)row * H;
    float acc = 0.f;
#pragma unroll
    for (int it = 0; it < 4; ++it) { int e = it*256 + lane*4; acc += dot4(ld4(er+e), ld4(u+e)); }
    acc = waveSum(acc);
    __shared__ float se[4];
    if (lane == 0) { energ[row] = acc; se[wid] = acc; }
    __syncthreads();
    if (t == 0) {
        float m = fmaxf(fmaxf(se[0], se[1]), fmaxf(se[2], se[3]));
        float s = __expf(se[0]-m) + __expf(se[1]-m) + __expf(se[2]-m) + __expf(se[3]-m);
        part_e[blockIdx.x] = make_float2(m, s);
    }
}

__global__ __launch_bounds__(256) void k_ctx(
        const float* __restrict__ enc, const float* __restrict__ energ,
        const float2* __restrict__ part_e, float* __restrict__ ctx) {
    const int t = threadIdx.x, wid = t >> 6, lane = t & 63;
    __shared__ float2 s2[4];
    __shared__ float sh[64];
    float2 a = part_e[t], b = part_e[t + 256];
    float m = a.x, s = a.y;
    omerge(m, s, b.x, b.y);
    waveOmerge(m, s);
    if (lane == 0) s2[wid] = make_float2(m, s);
    __syncthreads();
    float M = s2[0].x, S = s2[0].y;
#pragma unroll
    for (int q = 1; q < 4; ++q) omerge(M, S, s2[q].x, s2[q].y);
    const float invS = 1.f / S;
    const int j0 = (blockIdx.x >> 2) * 64;
    __syncthreads();
    if (t < 64) sh[t] = __expf(energ[j0 + t] - M) * invS;
    __syncthreads();
    const int k = (blockIdx.x & 3) * 256 + t;
    float acc = 0.f;
#pragma unroll 8
    for (int jj = 0; jj < 64; ++jj) acc += sh[jj] * enc[(size_t)(j0 + jj) * H + k];
    atomicAdd(&ctx[k], acc);
}

__global__ __launch_bounds__(256) void k_logits(
        const float* __restrict__ Wl, const float* __restrict__ vcat,
        const float* __restrict__ bl, float* __restrict__ logits,
        float2* __restrict__ part_l) {
    const int t = threadIdx.x, wid = t >> 6, lane = t & 63;
    const int gw = blockIdx.x * 4 + wid;
    float4 xv[8];
#pragma unroll
    for (int q = 0; q < 8; ++q) xv[q] = ld4(vcat + q * 256 + lane * 4);
    float lm = -INFINITY, ls = 0.f;
#pragma unroll
    for (int rr = 0; rr < 4; ++rr) {
        const int row = gw * 4 + rr;
        const float* wr = Wl + (size_t)row * (2 * H);
        float acc = 0.f;
#pragma unroll
        for (int q = 0; q < 8; ++q)
            acc += dot4(ld4(wr + q * 256 + lane * 4), xv[q]);
        acc = waveSum(acc);
        if (lane == 0) {
            float v = acc + bl[row];
            logits[row] = v;
            omerge(lm, ls, v, 1.f);
        }
    }
    __shared__ float2 s2[4];
    if (lane == 0) s2[wid] = make_float2(lm, ls);
    __syncthreads();
    if (t == 0) {
        float M = s2[0].x, S = s2[0].y;
#pragma unroll
        for (int q = 1; q < 4; ++q) omerge(M, S, s2[q].x, s2[q].y);
        part_l[blockIdx.x] = make_float2(M, S);
    }
}

__global__ __launch_bounds__(256) void k_final(
        const float* __restrict__ logits, const float2* __restrict__ part_l,
        float* __restrict__ out) {
    const int t = threadIdx.x, wid = t >> 6, lane = t & 63;
    __shared__ float2 s2[4];
    float m = -INFINITY, s = 0.f;
    for (int i = t; i < 2000; i += 256) {
        float2 p = part_l[i];
        omerge(m, s, p.x, p.y);
    }
    waveOmerge(m, s);
    if (lane == 0) s2[wid] = make_float2(m, s);
    __syncthreads();
    float M = s2[0].x, S = s2[0].y;
#pragma unroll
    for (int q = 1; q < 4; ++q) omerge(M, S, s2[q].x, s2[q].y);
    const float lse = M + logf(S);
    const int i = blockIdx.x * 256 + t;
    out[i] = logits[i] - lse;
}

extern "C" void kernel_launch(void* const* d_in, const int* in_sizes, int n_in,
                              void* d_out, int out_size, void* d_ws, size_t ws_size,
                              hipStream_t stream) {
    const int*   widx = (const int*)d_in[0];
    const float* lctx = (const float*)d_in[1];
    const float* h0   = (const float*)d_in[2];
    const float* enc  = (const float*)d_in[3];
    const float* emb  = (const float*)d_in[4];
    const float* W_ih = (const float*)d_in[5];
    const float* W_hh = (const float*)d_in[6];
    const float* b_ih = (const float*)d_in[7];
    const float* b_hh = (const float*)d_in[8];
    const float* Wa   = (const float*)d_in[9];
    // d_in[10] (ba): dropped — constant shift under softmax
    const float* Wl   = (const float*)d_in[11];
    const float* bl   = (const float*)d_in[12];
    float* out = (float*)d_out;
    float* ws  = (float*)d_ws;

    // guards: persistent path needs all blocks co-resident AND ws capacity
    int occ = 0, nCU = 0, dev = 0;
    hipGetDevice(&dev);
    hipDeviceGetAttribute(&nCU, hipDeviceAttributeMultiprocessorCount, dev);
    hipError_t oe = hipOccupancyMaxActiveBlocksPerMultiprocessor(
        &occ, (const void*)k_main, NTHR, 0);
    const bool persistent_ok = (oe == hipSuccess) && ((long)occ * nCU >= GRID2)
                             && (ws_size >= (size_t)WS_NEED_FLOATS * 4 + 4096);

    if (persistent_ok) {
        k_init<<<1, NTHR, 0, stream>>>(ws);
        k_main<<<GRID2, NTHR, 0, stream>>>(emb, lctx, h0, W_ih, W_hh, b_ih,
                                           b_hh, widx, enc, Wa, Wl, bl, ws, out);
    } else {
        float*  h      = ws;
        float*  ctx    = ws + 1024;
        float*  u      = ws + 2048;
        float*  energ  = ws + 3072;
        float2* part_e = (float2*)(ws + 5120);
        float2* part_l = (float2*)(ws + 6144);
        float*  logits = ws + 10240;
        k_lstm  <<<1024, 256, 0, stream>>>(emb, lctx, h0, W_ih, W_hh, b_ih, b_hh, widx, h, u, ctx);
        k_wa    <<<dim3(4, 32), 256, 0, stream>>>(Wa, h, u);
        k_energy<<<512, 256, 0, stream>>>(enc, u, energ, part_e);
        k_ctx   <<<128, 256, 0, stream>>>(enc, energ, part_e, ctx);
        k_logits<<<2000, 256, 0, stream>>>(Wl, ws /*vcat*/, bl, logits, part_l);
        k_final <<<125, 256, 0, stream>>>(logits, part_l, out);
    }
}